// Round 4
// baseline (549.132 us; speedup 1.0000x reference)
//
#include <hip/hip_runtime.h>

#define B_     16
#define N_IN_  6250
#define N_OUT_ 25000
#define C_     64
#define S_     9
#define NNZ_   75000
#define MT_    391   // ceil(N_OUT/64)

typedef __bf16 bf16x8 __attribute__((ext_vector_type(8)));
typedef float floatx4 __attribute__((ext_vector_type(4)));

// ---------------- CSR build ----------------

__global__ void hist_kernel(const int* __restrict__ rows, int* __restrict__ counts, int nnz) {
    int i = blockIdx.x * blockDim.x + threadIdx.x;
    if (i < nnz) atomicAdd(&counts[rows[i]], 1);
}

__global__ void scan1_kernel(const int* __restrict__ counts, int* __restrict__ offsets,
                             int* __restrict__ bsum, int n) {
    __shared__ int wsum[16];
    int t = threadIdx.x;
    int wid = t >> 6, lane = t & 63;
    int i = blockIdx.x * 1024 + t;
    int v = (i < n) ? counts[i] : 0;
    int s = v;
    #pragma unroll
    for (int d = 1; d < 64; d <<= 1) {
        int u = __shfl_up(s, d, 64);
        if (lane >= d) s += u;
    }
    if (lane == 63) wsum[wid] = s;
    __syncthreads();
    if (wid == 0 && lane < 16) {
        int ws = wsum[lane];
        #pragma unroll
        for (int d = 1; d < 16; d <<= 1) {
            int u = __shfl_up(ws, d, 64);
            if (lane >= d) ws += u;
        }
        wsum[lane] = ws;
    }
    __syncthreads();
    int wave_off = (wid == 0) ? 0 : wsum[wid - 1];
    int incl = s + wave_off;
    if (i < n) offsets[i] = incl - v;
    if (t == 1023) bsum[blockIdx.x] = incl;
}

__global__ void scan2_kernel(int* __restrict__ bsum, int* __restrict__ offsets, int nblk, int n) {
    if (threadIdx.x == 0) {
        int t = 0;
        for (int i = 0; i < nblk; ++i) { int v = bsum[i]; bsum[i] = t; t += v; }
        offsets[n] = t;
    }
}

__global__ void scan3_kernel(int* __restrict__ offsets, const int* __restrict__ bsum,
                             int* __restrict__ cursor, int n) {
    int i = blockIdx.x * 1024 + threadIdx.x;
    if (i < n) {
        int o = offsets[i] + bsum[blockIdx.x];
        offsets[i] = o;
        cursor[i] = o;
    }
}

__global__ void fill_kernel(const int* __restrict__ rows, const int* __restrict__ cols,
                            const float* __restrict__ vals, int* __restrict__ cursor,
                            int* __restrict__ ecol, float* __restrict__ eval, int nnz) {
    int i = blockIdx.x * blockDim.x + threadIdx.x;
    if (i < nnz) {
        int p = atomicAdd(&cursor[rows[i]], 1);
        ecol[p] = cols[i];
        eval[p] = vals[i];
    }
}

// ---------------- pooling: one batch per block, XCD-affine ----------------
// grid 1D = 8 * 12500. Block = 4 rows x 64 ch, one batch.
// xcd = bx&7; first half of grid = batches 0-7, second half = 8-15, so each
// XCD's L2 mostly holds its own x slab (1.6 MB x 2).
// pooled layout: [B][N_OUT][C] bf16.
__global__ __launch_bounds__(256) void pool_kernel(
        const float* __restrict__ x, const int* __restrict__ offsets,
        const int* __restrict__ ecol, const float* __restrict__ eval,
        __bf16* __restrict__ pooled) {
    int bx = blockIdx.x;
    int xcd = bx & 7;
    int rr = bx >> 3;                    // 0..12499
    int half = (rr >= 6250) ? 1 : 0;
    int rq = rr - half * 6250;           // 0..6249
    int b = xcd + 8 * half;
    int t = threadIdx.x;
    int row = rq * 4 + (t >> 6);
    int c = t & 63;

    int beg = offsets[row], end = offsets[row + 1];
    const float* xb = x + (size_t)b * N_IN_ * C_;
    float acc = 0.0f;
    for (int k = beg; k < end; ++k) {
        int col = ecol[k];               // wave-uniform -> broadcast
        float v = eval[k];
        acc += xb[(size_t)col * C_ + c] * v;
    }
    pooled[((size_t)b * N_OUT_ + row) * C_ + c] = (__bf16)acc;
}

// ---------------- W -> Wt (bf16, transposed [64][576]) ----------------
__global__ void convw_kernel(const float* __restrict__ W, __bf16* __restrict__ Wt) {
    int i = blockIdx.x * blockDim.x + threadIdx.x;   // over 576*64
    if (i < 576 * 64) {
        int k = i >> 6, n = i & 63;
        Wt[n * 576 + k] = (__bf16)W[i];
    }
}

// ---------------- spiral gather + GEMM + bias + ELU ----------------
// grid 1D = 8 * 782 (MT_*16 blocks). One batch per block, XCD-affine like pool.
// Block = 4 waves; wave = 64 rows x 16 cols (nt = wave id).
// B slice (18 frags, 72 VGPR) persistent in registers; A rotates through a
// 3-deep prefetch buffer with sched_barrier(0) pinning load-group positions.
// No LDS, no __syncthreads.
__global__ __launch_bounds__(256, 2) void gemm_kernel(
        const __bf16* __restrict__ pooled, const int* __restrict__ spiral,
        const __bf16* __restrict__ Wt, const float* __restrict__ bias,
        float* __restrict__ out) {
    int bx = blockIdx.x;
    int xcd = bx & 7;
    int rr = bx >> 3;                    // 0..781
    int half = (rr >= MT_) ? 1 : 0;
    int mt = rr - half * MT_;            // 0..390
    int b = xcd + 8 * half;

    int t = threadIdx.x;
    int wave = t >> 6, lane = t & 63;
    int quad = lane >> 4, l16 = lane & 15;
    int mbase = mt * 64;

    const __bf16* poolb = pooled + (size_t)b * N_OUT_ * C_;

    // spiral indices for this wave's 4 m-tiles (loaded once, independent)
    int src[4][S_];
    #pragma unroll
    for (int mi = 0; mi < 4; ++mi) {
        int m = mbase + mi * 16 + l16;
        int mc = (m < N_OUT_) ? m : 0;
        #pragma unroll
        for (int s = 0; s < S_; ++s) src[mi][s] = spiral[mc * S_ + s];
    }

    // persistent B fragments: this wave's 16-col slice of Wt, all of K
    bf16x8 Bf[S_][2];
    {
        const __bf16* wbase = Wt + (wave * 16 + l16) * 576 + quad * 8;
        #pragma unroll
        for (int s = 0; s < S_; ++s)
            #pragma unroll
            for (int kc = 0; kc < 2; ++kc)
                Bf[s][kc] = *reinterpret_cast<const bf16x8*>(wbase + s * 64 + kc * 32);
    }

    floatx4 acc[4] = {};                 // one 16x16 tile per mi
    bf16x8 Ab[3][4][2];                  // 3-deep rotating A buffers

    auto aload = [&](int s, bf16x8 (*buf)[2]) {
        #pragma unroll
        for (int mi = 0; mi < 4; ++mi)
            #pragma unroll
            for (int kc = 0; kc < 2; ++kc)
                buf[mi][kc] = *reinterpret_cast<const bf16x8*>(
                    poolb + (size_t)src[mi][s] * C_ + kc * 32 + quad * 8);
    };

    aload(0, Ab[0]);
    aload(1, Ab[1]);
    aload(2, Ab[2]);
    __builtin_amdgcn_sched_barrier(0);   // keep the 24-load prefetch ahead of MFMAs

    #pragma unroll
    for (int s = 0; s < S_; ++s) {
        bf16x8 (*cur)[2] = Ab[s % 3];
        #pragma unroll
        for (int mi = 0; mi < 4; ++mi) {
            acc[mi] = __builtin_amdgcn_mfma_f32_16x16x32_bf16(cur[mi][0], Bf[s][0], acc[mi], 0, 0, 0);
            acc[mi] = __builtin_amdgcn_mfma_f32_16x16x32_bf16(cur[mi][1], Bf[s][1], acc[mi], 0, 0, 0);
        }
        if (s + 3 < S_) {
            aload(s + 3, Ab[s % 3]);     // refill the buffer just consumed
            __builtin_amdgcn_sched_barrier(0);
        }
    }

    // epilogue: D[m = quad*4 + i][n = l16] per mi tile; col = wave*16 + l16
    float bn = bias[wave * 16 + l16];
    float* outb = out + (size_t)b * N_OUT_ * C_;
    #pragma unroll
    for (int mi = 0; mi < 4; ++mi) {
        #pragma unroll
        for (int i = 0; i < 4; ++i) {
            int m = mbase + mi * 16 + quad * 4 + i;
            if (m < N_OUT_) {
                float v = acc[mi][i] + bn;
                v = (v > 0.0f) ? v : expm1f(v);
                outb[(size_t)m * C_ + wave * 16 + l16] = v;
            }
        }
    }
}

extern "C" void kernel_launch(void* const* d_in, const int* in_sizes, int n_in,
                              void* d_out, int out_size, void* d_ws, size_t ws_size,
                              hipStream_t stream) {
    const float* x      = (const float*)d_in[0];
    const float* tvals  = (const float*)d_in[1];
    const int*   trow   = (const int*)d_in[2];
    const int*   tcol   = (const int*)d_in[3];
    const int*   spiral = (const int*)d_in[4];
    const float* W      = (const float*)d_in[5];
    const float* bias   = (const float*)d_in[6];
    float* out = (float*)d_out;

    char* ws = (char*)d_ws;
    size_t off = 0;
    auto alloc = [&](size_t bytes) -> void* {
        void* p = ws + off;
        off += (bytes + 255) & ~(size_t)255;
        return p;
    };
    __bf16* pooled  = (__bf16*)alloc((size_t)B_ * N_OUT_ * C_ * 2);   // 51.2 MB
    __bf16* Wt      = (__bf16*)alloc(576 * 64 * 2);
    int*    cursor  = (int*)alloc(N_OUT_ * 4);
    int*    offsets = (int*)alloc((N_OUT_ + 1) * 4);
    int*    ecol    = (int*)alloc(NNZ_ * 4);
    float*  eval    = (float*)alloc(NNZ_ * 4);
    int*    counts  = (int*)alloc(N_OUT_ * 4);
    int*    bsum    = (int*)alloc(32 * 4);

    const int NBLK = (N_OUT_ + 1023) / 1024;   // 25
    hipMemsetAsync(counts, 0, N_OUT_ * 4, stream);
    hist_kernel<<<(NNZ_ + 255) / 256, 256, 0, stream>>>(trow, counts, NNZ_);
    scan1_kernel<<<NBLK, 1024, 0, stream>>>(counts, offsets, bsum, N_OUT_);
    scan2_kernel<<<1, 64, 0, stream>>>(bsum, offsets, NBLK, N_OUT_);
    scan3_kernel<<<NBLK, 1024, 0, stream>>>(offsets, bsum, cursor, N_OUT_);
    fill_kernel<<<(NNZ_ + 255) / 256, 256, 0, stream>>>(trow, tcol, tvals, cursor, ecol, eval, NNZ_);
    pool_kernel<<<8 * 12500, 256, 0, stream>>>(x, offsets, ecol, eval, pooled);
    convw_kernel<<<(576 * 64 + 255) / 256, 256, 0, stream>>>(W, Wt);
    gemm_kernel<<<8 * (2 * MT_), 256, 0, stream>>>(pooled, spiral, Wt, bias, out);
}

// Round 5
// 300.048 us; speedup vs baseline: 1.8301x; 1.8301x over previous
//
#include <hip/hip_runtime.h>

#define B_     16
#define N_IN_  6250
#define N_OUT_ 25000
#define C_     64
#define S_     9
#define NNZ_   75000
#define MT_    391          // ceil(N_OUT/64)
#define BROW_  584          // LDS B row stride (576 + 8 pad -> conflict-free)

typedef __bf16 bf16x8 __attribute__((ext_vector_type(8)));
typedef float floatx4 __attribute__((ext_vector_type(4)));

__device__ inline void async_copy16(const void* g, void* l) {
    __builtin_amdgcn_global_load_lds(
        (const __attribute__((address_space(1))) void*)g,
        (__attribute__((address_space(3))) void*)l, 16, 0, 0);
}

// ---------------- CSR build ----------------

__global__ void hist_kernel(const int* __restrict__ rows, int* __restrict__ counts, int nnz) {
    int i = blockIdx.x * blockDim.x + threadIdx.x;
    if (i < nnz) atomicAdd(&counts[rows[i]], 1);
}

__global__ void scan1_kernel(const int* __restrict__ counts, int* __restrict__ offsets,
                             int* __restrict__ bsum, int n) {
    __shared__ int wsum[16];
    int t = threadIdx.x;
    int wid = t >> 6, lane = t & 63;
    int i = blockIdx.x * 1024 + t;
    int v = (i < n) ? counts[i] : 0;
    int s = v;
    #pragma unroll
    for (int d = 1; d < 64; d <<= 1) {
        int u = __shfl_up(s, d, 64);
        if (lane >= d) s += u;
    }
    if (lane == 63) wsum[wid] = s;
    __syncthreads();
    if (wid == 0 && lane < 16) {
        int ws = wsum[lane];
        #pragma unroll
        for (int d = 1; d < 16; d <<= 1) {
            int u = __shfl_up(ws, d, 64);
            if (lane >= d) ws += u;
        }
        wsum[lane] = ws;
    }
    __syncthreads();
    int wave_off = (wid == 0) ? 0 : wsum[wid - 1];
    int incl = s + wave_off;
    if (i < n) offsets[i] = incl - v;
    if (t == 1023) bsum[blockIdx.x] = incl;
}

__global__ void scan2_kernel(int* __restrict__ bsum, int* __restrict__ offsets, int nblk, int n) {
    if (threadIdx.x == 0) {
        int t = 0;
        for (int i = 0; i < nblk; ++i) { int v = bsum[i]; bsum[i] = t; t += v; }
        offsets[n] = t;
    }
}

__global__ void scan3_kernel(int* __restrict__ offsets, const int* __restrict__ bsum,
                             int* __restrict__ cursor, int n) {
    int i = blockIdx.x * 1024 + threadIdx.x;
    if (i < n) {
        int o = offsets[i] + bsum[blockIdx.x];
        offsets[i] = o;
        cursor[i] = o;
    }
}

__global__ void fill_kernel(const int* __restrict__ rows, const int* __restrict__ cols,
                            const float* __restrict__ vals, int* __restrict__ cursor,
                            int* __restrict__ ecol, float* __restrict__ eval, int nnz) {
    int i = blockIdx.x * blockDim.x + threadIdx.x;
    if (i < nnz) {
        int p = atomicAdd(&cursor[rows[i]], 1);
        ecol[p] = cols[i];
        eval[p] = vals[i];
    }
}

// ---------------- pooling (CSR gather), all batches per block ----------------
// grid: N_OUT blocks, block 256. Thread (bq, c): batches bq*4..bq*4+3, channel c.
// MLP = 4 independent gathers per nnz per thread. Output layout [B][N_OUT][C].
__global__ __launch_bounds__(256) void pool_kernel(
        const float* __restrict__ x, const int* __restrict__ offsets,
        const int* __restrict__ ecol, const float* __restrict__ eval,
        __bf16* __restrict__ pooled) {
    __shared__ int   scol[64];
    __shared__ float sval[64];
    int row = blockIdx.x;
    int t = threadIdx.x;
    int c = t & 63, bq = t >> 6;
    int beg = offsets[row], end = offsets[row + 1];
    int count = end - beg;

    float acc[4] = {0.f, 0.f, 0.f, 0.f};
    for (int base = 0; base < count; base += 64) {
        int nb = min(64, count - base);
        if (t < nb) {
            scol[t] = ecol[beg + base + t];
            sval[t] = eval[beg + base + t];
        }
        __syncthreads();
        for (int k = 0; k < nb; ++k) {
            int col = scol[k];
            float v = sval[k];
            const float* xp = x + ((size_t)col * C_ + c);
            #pragma unroll
            for (int j = 0; j < 4; ++j) {
                acc[j] += xp[(size_t)(bq * 4 + j) * N_IN_ * C_] * v;
            }
        }
        __syncthreads();
    }
    #pragma unroll
    for (int j = 0; j < 4; ++j) {
        pooled[((size_t)(bq * 4 + j) * N_OUT_ + row) * C_ + c] = (__bf16)acc[j];
    }
}

// ---------------- W -> Wt (bf16, transposed [64][576]) ----------------
__global__ void convw_kernel(const float* __restrict__ W, __bf16* __restrict__ Wt) {
    int i = blockIdx.x * blockDim.x + threadIdx.x;   // over 576*64
    if (i < 576 * 64) {
        int k = i >> 6, n = i & 63;
        Wt[n * 576 + k] = (__bf16)W[i];
    }
}

// ---------------- spiral gather + GEMM + bias + ELU ----------------
// grid 1D = 8 * (2*MT_), XCD-affine: bx&7 = xcd, one batch per block.
// Block = 4 waves; wave = 16 m-rows x 64 cols. All of Wt staged once into LDS
// (async global_load_lds, padded rows); K-loop is barrier-free; A fragments
// register double-buffered (16 VGPRs) with sched_barrier pinning.
__global__ __launch_bounds__(256, 2) void gemm_kernel(
        const __bf16* __restrict__ pooled, const int* __restrict__ spiral,
        const __bf16* __restrict__ Wt, const float* __restrict__ bias,
        float* __restrict__ out) {
    __shared__ __bf16 Bs[64 * BROW_];   // 74752 B

    int bx = blockIdx.x;
    int xcd = bx & 7;
    int rr = bx >> 3;                    // 0..781
    int half = (rr >= MT_) ? 1 : 0;
    int mt = rr - half * MT_;            // 0..390
    int b = xcd + 8 * half;

    int t = threadIdx.x;
    int wave = t >> 6, lane = t & 63;
    int quad = lane >> 4, l16 = lane & 15;
    int mbase = mt * 64 + wave * 16;
    int m = mbase + l16;
    int mc = (m < N_OUT_) ? m : 0;

    // stage Wt -> Bs (padded): LDS offset j*16 maps to col=j/73, rem=j%73.
    // Pad region (rem >= 72) loads garbage, never read. 4672 x 16B total.
    for (int j = t; j < (64 * BROW_ * 2) / 16; j += 256) {
        int col = j / 73;
        int rem = j - col * 73;
        async_copy16((const char*)Wt + col * 1152 + rem * 16,
                     (char*)Bs + j * 16);
    }

    // per-lane spiral indices (independent loads, overlap the staging)
    int src[S_];
    #pragma unroll
    for (int s = 0; s < S_; ++s) src[s] = spiral[mc * S_ + s];

    const __bf16* poolb = pooled + (size_t)b * N_OUT_ * C_;

    __syncthreads();   // staging drained (single barrier of the kernel)

    floatx4 acc[4] = {};
    bf16x8 Acur[2], Anxt[2];

    auto loadA = [&](int s, bf16x8* A) {
        const __bf16* p = poolb + (size_t)src[s] * C_ + quad * 8;
        A[0] = *reinterpret_cast<const bf16x8*>(p);
        A[1] = *reinterpret_cast<const bf16x8*>(p + 32);
    };

    loadA(0, Acur);
    #pragma unroll
    for (int s = 0; s < S_; ++s) {
        if (s + 1 < S_) {
            loadA(s + 1, (s & 1) ? Acur : Anxt);   // prefetch next step
            __builtin_amdgcn_sched_barrier(0);     // pin: loads stay ahead of MFMAs
        }
        bf16x8* A = (s & 1) ? Anxt : Acur;
        #pragma unroll
        for (int kc = 0; kc < 2; ++kc) {
            #pragma unroll
            for (int nt = 0; nt < 4; ++nt) {
                bf16x8 bb = *reinterpret_cast<const bf16x8*>(
                    &Bs[(nt * 16 + l16) * BROW_ + s * 64 + kc * 32 + quad * 8]);
                acc[nt] = __builtin_amdgcn_mfma_f32_16x16x32_bf16(A[kc], bb, acc[nt], 0, 0, 0);
            }
        }
    }

    // epilogue: D[m = quad*4 + i][n = l16] per nt tile
    float* outb = out + (size_t)b * N_OUT_ * C_;
    #pragma unroll
    for (int nt = 0; nt < 4; ++nt) {
        float bn = bias[nt * 16 + l16];
        #pragma unroll
        for (int i = 0; i < 4; ++i) {
            int mm = mbase + quad * 4 + i;
            if (mm < N_OUT_) {
                float v = acc[nt][i] + bn;
                v = (v > 0.0f) ? v : expm1f(v);
                outb[(size_t)mm * C_ + nt * 16 + l16] = v;
            }
        }
    }
}

extern "C" void kernel_launch(void* const* d_in, const int* in_sizes, int n_in,
                              void* d_out, int out_size, void* d_ws, size_t ws_size,
                              hipStream_t stream) {
    const float* x      = (const float*)d_in[0];
    const float* tvals  = (const float*)d_in[1];
    const int*   trow   = (const int*)d_in[2];
    const int*   tcol   = (const int*)d_in[3];
    const int*   spiral = (const int*)d_in[4];
    const float* W      = (const float*)d_in[5];
    const float* bias   = (const float*)d_in[6];
    float* out = (float*)d_out;

    char* ws = (char*)d_ws;
    size_t off = 0;
    auto alloc = [&](size_t bytes) -> void* {
        void* p = ws + off;
        off += (bytes + 255) & ~(size_t)255;
        return p;
    };
    __bf16* pooled  = (__bf16*)alloc((size_t)B_ * N_OUT_ * C_ * 2);   // 51.2 MB
    __bf16* Wt      = (__bf16*)alloc(576 * 64 * 2);
    int*    cursor  = (int*)alloc(N_OUT_ * 4);
    int*    offsets = (int*)alloc((N_OUT_ + 1) * 4);
    int*    ecol    = (int*)alloc(NNZ_ * 4);
    float*  eval    = (float*)alloc(NNZ_ * 4);
    int*    counts  = (int*)alloc(N_OUT_ * 4);
    int*    bsum    = (int*)alloc(32 * 4);

    const int NBLK = (N_OUT_ + 1023) / 1024;   // 25
    hipMemsetAsync(counts, 0, N_OUT_ * 4, stream);
    hist_kernel<<<(NNZ_ + 255) / 256, 256, 0, stream>>>(trow, counts, NNZ_);
    scan1_kernel<<<NBLK, 1024, 0, stream>>>(counts, offsets, bsum, N_OUT_);
    scan2_kernel<<<1, 64, 0, stream>>>(bsum, offsets, NBLK, N_OUT_);
    scan3_kernel<<<NBLK, 1024, 0, stream>>>(offsets, bsum, cursor, N_OUT_);
    fill_kernel<<<(NNZ_ + 255) / 256, 256, 0, stream>>>(trow, tcol, tvals, cursor, ecol, eval, NNZ_);
    pool_kernel<<<N_OUT_, 256, 0, stream>>>(x, offsets, ecol, eval, pooled);
    convw_kernel<<<(576 * 64 + 255) / 256, 256, 0, stream>>>(W, Wt);
    gemm_kernel<<<8 * (2 * MT_), 256, 0, stream>>>(pooled, spiral, Wt, bias, out);
}